// Round 7
// baseline (541.228 us; speedup 1.0000x reference)
//
#include <hip/hip_runtime.h>
#include <math.h>

#define K_CODES 512
#define DIM 64
#define ROWS_PER_BLOCK 128   // 256 threads: t<128 scan k[0,256), t>=128 scan k[256,512)

// numpy pairwise sum (n=64 path): 8 strided accumulators, sequential adds
// within each, then pairwise tree combine. Contract OFF. FROZEN: bit-exact
// vs np across R1-R6 (absmax 0.0); d is quantized to ulp(64)=7.6e-6 with
// k-spread ~0.018 -> ~20% of rows have sub-ulp top-2 gaps; any reorder fails.
__device__ __forceinline__ float np_pairwise_sumsq(const float* v) {
#pragma clang fp contract(off)
    float p[DIM];
#pragma unroll
    for (int j = 0; j < DIM; ++j) p[j] = v[j] * v[j];
    float r[8];
#pragma unroll
    for (int a = 0; a < 8; ++a) r[a] = p[a];
#pragma unroll
    for (int i = 8; i < DIM; i += 8) {
#pragma unroll
        for (int a = 0; a < 8; ++a) r[a] = r[a] + p[i + a];
    }
    return ((r[0] + r[1]) + (r[2] + r[3])) + ((r[4] + r[5]) + (r[6] + r[7]));
}

// Pre-kernel: esq[c] = ||codebook[c]||^2 into d_ws (np order), padded to 544
// floats (the main loop's esq s_load prefetches one group past the end).
__global__ void vq_esq_pre(const float* __restrict__ cb, float* __restrict__ esq) {
    const int c = threadIdx.x;
    if (c < K_CODES) esq[c] = np_pairwise_sumsq(cb + (size_t)c * DIM);
    else if (c < 544) esq[c] = 0.0f;
}

// K-loop in inline asm with hard registers (R2-R6: the backend refused to
// keep zr in arch VGPRs under every register/occupancy control; and mixing
// s_load+ds_read in the loop forces lgkmcnt(0) drains every iteration).
// Map: v16-79 zr | v80-95 bufA / v96-111 bufB (16-float codebook chunks,
// VMEM broadcast loads, vmcnt(4) chunk pipeline) | v112-119 accs | v120 dmin
// v121 best v122 k v123/124 scratch v125 zero-voff v126 zsq.
// esq via s_load_dwordx4, prefetched one 4-iter group ahead (only lgkm op).
__global__ __launch_bounds__(256)
void vq_argmin_gather(
    const float* __restrict__ z, const float* __restrict__ cb,
    const float* __restrict__ esq,
    float* __restrict__ out, int n_rows) {
#pragma clang fp contract(off)
    __shared__ float red_d[ROWS_PER_BLOCK];
    __shared__ int   red_b[ROWS_PER_BLOCK];
    __shared__ int   best_lds[ROWS_PER_BLOCK];

    const int t  = threadIdx.x;
    const int tr = t & (ROWS_PER_BLOCK - 1);
    const int row = blockIdx.x * ROWS_PER_BLOCK + tr;
    const int k0 = __builtin_amdgcn_readfirstlane((t >> 7) << 8);

    const float* cbase = cb + (size_t)k0 * DIM;   // wave-uniform
    const float* esqb  = esq + k0;                // wave-uniform
    const float* zrow  = z + (size_t)row * DIM;   // per-lane

    float dmin;
    int best;

    asm volatile(
        // ---------------- prologue ----------------
        "v_mov_b32 v125, 0\n\t"
        "global_load_dwordx4 v[16:19],  %[zrow], off offset:0\n\t"
        "global_load_dwordx4 v[20:23],  %[zrow], off offset:16\n\t"
        "global_load_dwordx4 v[24:27],  %[zrow], off offset:32\n\t"
        "global_load_dwordx4 v[28:31],  %[zrow], off offset:48\n\t"
        "global_load_dwordx4 v[32:35],  %[zrow], off offset:64\n\t"
        "global_load_dwordx4 v[36:39],  %[zrow], off offset:80\n\t"
        "global_load_dwordx4 v[40:43],  %[zrow], off offset:96\n\t"
        "global_load_dwordx4 v[44:47],  %[zrow], off offset:112\n\t"
        "global_load_dwordx4 v[48:51],  %[zrow], off offset:128\n\t"
        "global_load_dwordx4 v[52:55],  %[zrow], off offset:144\n\t"
        "global_load_dwordx4 v[56:59],  %[zrow], off offset:160\n\t"
        "global_load_dwordx4 v[60:63],  %[zrow], off offset:176\n\t"
        "global_load_dwordx4 v[64:67],  %[zrow], off offset:192\n\t"
        "global_load_dwordx4 v[68:71],  %[zrow], off offset:208\n\t"
        "global_load_dwordx4 v[72:75],  %[zrow], off offset:224\n\t"
        "global_load_dwordx4 v[76:79],  %[zrow], off offset:240\n\t"
        "s_mov_b64 s[16:17], %[cb]\n\t"
        "s_mov_b64 s[34:35], s[16:17]\n\t"
        "s_mov_b64 s[18:19], %[esq]\n\t"
        "s_mov_b32 s21, %[k0]\n\t"
        "s_mov_b32 s20, 0\n\t"
        "s_load_dwordx4 s[28:31], s[18:19], 0x0\n\t"   // esq group 0
        "s_waitcnt vmcnt(0)\n\t"                        // zr resident
        // chunks m0->A, m1->B (row 0 of this half)
        "global_load_dwordx4 v[80:83],   v125, s[16:17] offset:0\n\t"
        "global_load_dwordx4 v[84:87],   v125, s[16:17] offset:16\n\t"
        "global_load_dwordx4 v[88:91],   v125, s[16:17] offset:32\n\t"
        "global_load_dwordx4 v[92:95],   v125, s[16:17] offset:48\n\t"
        "global_load_dwordx4 v[96:99],   v125, s[16:17] offset:64\n\t"
        "global_load_dwordx4 v[100:103], v125, s[16:17] offset:80\n\t"
        "global_load_dwordx4 v[104:107], v125, s[16:17] offset:96\n\t"
        "global_load_dwordx4 v[108:111], v125, s[16:17] offset:112\n\t"
        // zsq in np order (overlaps the loads above)
        ".set AA, 0\n"
        ".rept 8\n\t"
        "v_mul_f32 v[112+AA], v[16+AA], v[16+AA]\n"
        ".set AA, AA+1\n"
        ".endr\n"
        ".set II, 8\n"
        ".rept 7\n"
        ".set AA, 0\n"
        ".rept 8\n\t"
        "v_mul_f32 v[123+(AA&1)], v[16+II+AA], v[16+II+AA]\n\t"
        "v_add_f32 v[112+AA], v[112+AA], v[123+(AA&1)]\n"
        ".set AA, AA+1\n"
        ".endr\n"
        ".set II, II+8\n"
        ".endr\n\t"
        "v_add_f32 v112, v112, v113\n\t"
        "v_add_f32 v114, v114, v115\n\t"
        "v_add_f32 v116, v116, v117\n\t"
        "v_add_f32 v118, v118, v119\n\t"
        "v_add_f32 v112, v112, v114\n\t"
        "v_add_f32 v116, v116, v118\n\t"
        "v_add_f32 v112, v112, v116\n\t"
        "v_mov_b32 v126, v112\n\t"
        "v_mov_b32 v120, 0x7f800000\n\t"   // dmin = +inf
        "v_mov_b32 v121, s21\n\t"          // best = k0
        // ---------------- main loop: 64 groups x 4 iters ----------------
        "1:\n\t"
        "s_waitcnt lgkmcnt(0)\n\t"                 // esq group g in B
        "s_mov_b64 s[24:25], s[28:29]\n\t"
        "s_mov_b64 s[26:27], s[30:31]\n\t"
        "s_add_u32 s18, s18, 16\n\t"
        "s_addc_u32 s19, s19, 0\n\t"
        "s_load_dwordx4 s[28:31], s[18:19], 0x0\n"  // esq group g+1
        ".set RR, 0\n"
        ".rept 4\n"
        ".set CC, 0\n"
        ".rept 4\n\t"
        "s_waitcnt vmcnt(4)\n"
        ".set EE, 0\n"
        ".rept 16\n"
        ".if (CC==0)&&(EE<8)\n\t"
        "v_mul_f32 v[112+(EE&7)], v[16+16*CC+EE], v[80+16*(CC&1)+EE]\n"
        ".else\n\t"
        "v_fmac_f32 v[112+(EE&7)], v[16+16*CC+EE], v[80+16*(CC&1)+EE]\n"
        ".endif\n"
        ".set EE, EE+1\n"
        ".endr\n"
        // prefetch chunk m=4*kk+CC+2 (same buffer parity). Last iter of
        // group 63 would read past this half: route r3c2/r3c3 through
        // s[36:37] = cselect(g<63 ? live base : cb start) -> dead-but-safe.
        ".if RR==3\n"
        ".if CC==2\n\t"
        "s_cmp_lt_u32 s20, 63\n\t"
        "s_cselect_b64 s[36:37], s[16:17], s[34:35]\n\t"
        "global_load_dwordx4 v[80:83], v125, s[36:37] offset:128\n\t"
        "global_load_dwordx4 v[84:87], v125, s[36:37] offset:144\n\t"
        "global_load_dwordx4 v[88:91], v125, s[36:37] offset:160\n\t"
        "global_load_dwordx4 v[92:95], v125, s[36:37] offset:176\n"
        ".endif\n"
        ".if CC==3\n\t"
        "global_load_dwordx4 v[96:99],   v125, s[36:37] offset:192\n\t"
        "global_load_dwordx4 v[100:103], v125, s[36:37] offset:208\n\t"
        "global_load_dwordx4 v[104:107], v125, s[36:37] offset:224\n\t"
        "global_load_dwordx4 v[108:111], v125, s[36:37] offset:240\n"
        ".endif\n"
        ".if CC<2\n\t"
        "global_load_dwordx4 v[80+16*(CC&1):80+16*(CC&1)+3],   v125, s[16:17] offset:128\n\t"
        "global_load_dwordx4 v[84+16*(CC&1):84+16*(CC&1)+3],   v125, s[16:17] offset:144\n\t"
        "global_load_dwordx4 v[88+16*(CC&1):88+16*(CC&1)+3],   v125, s[16:17] offset:160\n\t"
        "global_load_dwordx4 v[92+16*(CC&1):92+16*(CC&1)+3],   v125, s[16:17] offset:176\n"
        ".endif\n"
        ".else\n\t"
        "global_load_dwordx4 v[80+16*(CC&1):80+16*(CC&1)+3],   v125, s[16:17] offset:128\n\t"
        "global_load_dwordx4 v[84+16*(CC&1):84+16*(CC&1)+3],   v125, s[16:17] offset:144\n\t"
        "global_load_dwordx4 v[88+16*(CC&1):88+16*(CC&1)+3],   v125, s[16:17] offset:160\n\t"
        "global_load_dwordx4 v[92+16*(CC&1):92+16*(CC&1)+3],   v125, s[16:17] offset:176\n"
        ".endif\n\t"
        "s_add_u32 s16, s16, 64\n\t"
        "s_addc_u32 s17, s17, 0\n"
        ".set CC, CC+1\n"
        ".endr\n\t"
        // iter epilogue: np combine tree + d + argmin (FROZEN arithmetic)
        "v_add_f32 v112, v112, v113\n\t"
        "v_add_f32 v114, v114, v115\n\t"
        "v_add_f32 v116, v116, v117\n\t"
        "v_add_f32 v118, v118, v119\n\t"
        "v_add_f32 v112, v112, v114\n\t"
        "v_add_f32 v116, v116, v118\n\t"
        "v_add_f32 v112, v112, v116\n\t"          // dot
        "v_mul_f32 v123, 2.0, v112\n\t"           // m = 2*dot (exact)
        "v_add_f32 v124, s[24+RR], v126\n\t"      // tkv = esq_k + zsq
        "v_sub_f32 v123, v124, v123\n\t"          // d = tkv - m
        "v_cmp_lt_f32 vcc, v123, v120\n\t"        // strict <
        "v_mov_b32 v122, s21\n\t"
        "v_cndmask_b32 v120, v120, v123, vcc\n\t"
        "v_cndmask_b32 v121, v121, v122, vcc\n\t"
        "s_add_u32 s21, s21, 1\n"
        ".set RR, RR+1\n"
        ".endr\n\t"
        "s_add_u32 s20, s20, 1\n\t"
        "s_cmp_lt_u32 s20, 64\n\t"
        "s_cbranch_scc1 1b\n\t"
        // ---------------- epilogue ----------------
        "v_mov_b32 %[dmin], v120\n\t"
        "v_mov_b32 %[best], v121\n\t"
        "s_waitcnt vmcnt(0) lgkmcnt(0)\n\t"
        : [dmin] "=&v"(dmin), [best] "=&v"(best)
        : [cb] "s"(cbase), [esq] "s"(esqb), [k0] "s"(k0), [zrow] "v"(zrow)
        : "memory", "vcc", "scc",
          "v16","v17","v18","v19","v20","v21","v22","v23","v24","v25","v26","v27",
          "v28","v29","v30","v31","v32","v33","v34","v35","v36","v37","v38","v39",
          "v40","v41","v42","v43","v44","v45","v46","v47","v48","v49","v50","v51",
          "v52","v53","v54","v55","v56","v57","v58","v59","v60","v61","v62","v63",
          "v64","v65","v66","v67","v68","v69","v70","v71","v72","v73","v74","v75",
          "v76","v77","v78","v79","v80","v81","v82","v83","v84","v85","v86","v87",
          "v88","v89","v90","v91","v92","v93","v94","v95","v96","v97","v98","v99",
          "v100","v101","v102","v103","v104","v105","v106","v107","v108","v109",
          "v110","v111","v112","v113","v114","v115","v116","v117","v118","v119",
          "v120","v121","v122","v123","v124","v125","v126",
          "s16","s17","s18","s19","s20","s21","s22","s23","s24","s25","s26","s27",
          "s28","s29","s30","s31","s32","s33","s34","s35","s36","s37");

    // Combine the two k-halves. Upper half publishes, lower half reduces.
    if (t >= ROWS_PER_BLOCK) {
        red_d[tr] = dmin;
        red_b[tr] = best;
    }
    __syncthreads();
    if (t < ROWS_PER_BLOCK) {
        // strict <: on ties the lower-k half (this thread) wins, matching
        // global first-index argmin semantics.
        int b = (red_d[tr] < dmin) ? red_b[tr] : best;
        best_lds[tr] = b;
    }
    __syncthreads();

    // Block-cooperative coalesced write of both outputs.
    const float4* cb4 = (const float4*)cb;
    float4* o = (float4*)out;
    const size_t out1_off = (size_t)n_rows * (DIM / 4);
    const size_t grow = (size_t)blockIdx.x * ROWS_PER_BLOCK * (DIM / 4);
#pragma unroll
    for (int i = t; i < ROWS_PER_BLOCK * (DIM / 4); i += 256) {
        const int r = i >> 4;
        const int j = i & 15;
        const float4 v = cb4[(size_t)best_lds[r] * (DIM / 4) + j];
        const size_t g = grow + (size_t)r * (DIM / 4) + j;
        o[g] = v;
        o[g + out1_off] = v;
    }
}

extern "C" void kernel_launch(void* const* d_in, const int* in_sizes, int n_in,
                              void* d_out, int out_size, void* d_ws, size_t ws_size,
                              hipStream_t stream) {
    const float* z  = (const float*)d_in[0];   // [N, 64] fp32
    const float* cb = (const float*)d_in[1];   // [512, 64] fp32
    float* out = (float*)d_out;                // [2 * N * 64] fp32
    float* esq = (float*)d_ws;                 // 544 floats scratch

    const int n_rows = in_sizes[0] / DIM;      // 131072
    const int grid = n_rows / ROWS_PER_BLOCK;  // 1024 blocks of 256

    vq_esq_pre<<<dim3(1), dim3(576), 0, stream>>>(cb, esq);
    vq_argmin_gather<<<dim3(grid), dim3(256), 0, stream>>>(z, cb, esq, out, n_rows);
}